// Round 18
// baseline (1564.225 us; speedup 1.0000x reference)
//
#include <hip/hip_runtime.h>
#include <hip/hip_bf16.h>
#include <math.h>

typedef __bf16 bf16_t;
typedef __bf16 bf16x8 __attribute__((ext_vector_type(8)));
typedef __bf16 bf16x4 __attribute__((ext_vector_type(4)));
typedef float f32x4 __attribute__((ext_vector_type(4)));
typedef float f32x16 __attribute__((ext_vector_type(16)));
typedef unsigned short u16;
typedef unsigned int u32;
typedef u16 u16x8 __attribute__((ext_vector_type(8)));
typedef u32 u32x4 __attribute__((ext_vector_type(4)));

#define NDEPTH 4
#define DIM 1024
#define NHEADS 16
#define MLP_DIM 4096
#define CTXD 768
#define NTOK 4096
#define NCTX 2048
// softmax in exp2 domain: p = 2^(s*SC2), SC2 = 0.125 * log2(e), folded into Q
#define ATT_SC2 0.18033688011112042f

__device__ inline void gload_lds16(const void* g, void* l) {
  __builtin_amdgcn_global_load_lds(
      (const __attribute__((address_space(1))) void*)g,
      (__attribute__((address_space(3))) void*)l, 16, 0, 0);
}

__device__ inline u32 packbf2(float a, float b) {
  union { bf16_t h[2]; u32 w; } u;
  u.h[0] = (bf16_t)a; u.h[1] = (bf16_t)b;
  return u.w;
}

// bijective XCD swizzle (valid when nwg % 8 == 0; all launches here comply)
__device__ inline void xcd_swizzle(int& bx, int& by) {
  const int gx = gridDim.x, nwg = gx * gridDim.y;
  int id = by * gx + bx;
  id = (id & 7) * (nwg >> 3) + (id >> 3);
  bx = id % gx; by = id / gx;
}

// GELU, tanh form via exp2+rcp: 0.5v(1+tanh(c1(v+c2 v^3))) = v*(1 - 1/(e^{2y}+1)).
__device__ inline float gelu_fast(float v) {
  float y = 0.79788456f * (v + 0.044715f * v * v * v);
  float t = exp2f(y * 2.885390082f);           // e^{2y}
  return v * (1.f - 1.f / (t + 1.f));
}

// Epilogues. Residual stream lives in BF16:
//   0: bf16 out            2: bias+GELU, bf16 out
//   3: bias + bf16 res -> bf16 out        (steady-state residual)
//   4: bias + fp32 res -> bf16 out        (layer-0 sa_o, res = input x)
//   5: bias + bf16 res -> fp32 out        (final ff2 -> d_out)
template<int EPI>
__device__ inline void epi_store(void* outp, const float* bias, const void* resv,
                                 int row, int col, int N, float v) {
  size_t idx = (size_t)row * N + col;
  if (EPI == 0) {
    ((bf16_t*)outp)[idx] = (bf16_t)v;
  } else if (EPI == 2) {
    ((bf16_t*)outp)[idx] = (bf16_t)gelu_fast(v + bias[col]);
  } else if (EPI == 3) {
    float r = (float)((const bf16_t*)resv)[idx];
    ((bf16_t*)outp)[idx] = (bf16_t)(v + bias[col] + r);
  } else if (EPI == 4) {
    float r = ((const float*)resv)[idx];
    ((bf16_t*)outp)[idx] = (bf16_t)(v + bias[col] + r);
  } else if (EPI == 5) {
    float r = (float)((const bf16_t*)resv)[idx];
    ((float*)outp)[idx] = v + bias[col] + r;
  }
}

// T2 bank-conflict swizzle for [rows][32bf16] GEMM LDS tiles (2-bit slot),
// applied identically on the staging SOURCE column and every read (involution).
__device__ inline int swz_slot(int row, int slot) { return slot ^ ((row >> 1) & 3); }

// ---------------- GEMM 128x128 tile, 512 thr (8 waves 2x4, per-wave 64x32) ----
// 4-buffer pipeline, 3-DEEP prefetch (stage t+3, counted vmcnt(4)): each
// tile's loads get ~2.5 iterations to land (same fix that improved gemm64).
// LDS 64 KB -> 2 blocks/CU; these kernels are latency-bound (VALUBusy ~16%),
// so pipeline depth beats occupancy here.
template<int EPI>
__global__ __launch_bounds__(512) void gemm_bf16(
    const bf16_t* __restrict__ A, const bf16_t* __restrict__ Bt,
    const float* __restrict__ bias, const void* __restrict__ res,
    void* __restrict__ outp, int M, int N, int K)
{
  __shared__ alignas(16) bf16_t As[4 * 128 * 32];
  __shared__ alignas(16) bf16_t Bs[4 * 128 * 32];
  const int tid = threadIdx.x, lane = tid & 63, wave = tid >> 6;
  int bx = blockIdx.x, by = blockIdx.y;
  xcd_swizzle(bx, by);
  const int wr = wave >> 2, wc = wave & 3;
  const int l15 = lane & 15, l4 = lane >> 4;

  const int srow = tid >> 2;
  const int soff = swz_slot(srow, tid & 3) * 8;
  const bf16_t* gA = A + (size_t)by * 128 * K + (size_t)srow * K + soff;
  const bf16_t* gB = Bt + (size_t)bx * 128 * K + (size_t)srow * K + soff;
  bf16_t* lA = &As[tid * 8];
  bf16_t* lB = &Bs[tid * 8];

  f32x4 acc[4][2] = {};

  int aoff[4], boff[2];
#pragma unroll
  for (int mi = 0; mi < 4; ++mi) {
    int row = wr * 64 + mi * 16 + l15;
    aoff[mi] = row * 32 + swz_slot(row, l4) * 8;
  }
#pragma unroll
  for (int ni = 0; ni < 2; ++ni) {
    int row = wc * 32 + ni * 16 + l15;
    boff[ni] = row * 32 + swz_slot(row, l4) * 8;
  }

  auto compute = [&](int cur) {   // cur is a literal at every call site
    bf16x8 af[4], bfr[2];
#pragma unroll
    for (int mi = 0; mi < 4; ++mi)
      af[mi] = *(const bf16x8*)&As[cur * 4096 + aoff[mi]];
#pragma unroll
    for (int ni = 0; ni < 2; ++ni)
      bfr[ni] = *(const bf16x8*)&Bs[cur * 4096 + boff[ni]];
#pragma unroll
    for (int mi = 0; mi < 4; ++mi)
#pragma unroll
      for (int ni = 0; ni < 2; ++ni)
        acc[mi][ni] = __builtin_amdgcn_mfma_f32_16x16x32_bf16(af[mi], bfr[ni], acc[mi][ni], 0, 0, 0);
  };

  const int nk = K >> 5;   // == 32 for all gemm_bf16 launches (K=1024), nk % 4 == 0

  // prologue: stage tiles 0,1,2 into buffers 0,1,2
  gload_lds16(gA, lA);                 gload_lds16(gB, lB);
  gload_lds16(gA + 32, lA + 4096);     gload_lds16(gB + 32, lB + 4096);
  gload_lds16(gA + 64, lA + 2 * 4096); gload_lds16(gB + 64, lB + 2 * 4096);
  asm volatile("s_waitcnt vmcnt(4)" ::: "memory");   // tile 0 landed
  __builtin_amdgcn_s_barrier();
  __builtin_amdgcn_sched_barrier(0);
  gA += 96; gB += 96;   // stage base now at tile 3

  for (int j = 0; j < (nk >> 2) - 1; ++j) {
#pragma unroll
    for (int r = 0; r < 4; ++r) {     // t = 4j + r; compute buf r, stage buf (r+3)&3
      gload_lds16(gA + r * 32, lA + ((r + 3) & 3) * 4096);
      gload_lds16(gB + r * 32, lB + ((r + 3) & 3) * 4096);
      compute(r);
      asm volatile("s_waitcnt vmcnt(4)" ::: "memory");  // next buf ready; 2 stages in flight
      __builtin_amdgcn_s_barrier();
      __builtin_amdgcn_sched_barrier(0);
    }
    gA += 128; gB += 128;
  }
  // last group: t = nk-4 .. nk-1 (buffers 0..3); only t=nk-4 stages (tile nk-1 -> buf 3)
  gload_lds16(gA, lA + 3 * 4096);
  gload_lds16(gB, lB + 3 * 4096);
  compute(0);
  asm volatile("s_waitcnt vmcnt(4)" ::: "memory");
  __builtin_amdgcn_s_barrier();
  __builtin_amdgcn_sched_barrier(0);
  compute(1);
  asm volatile("s_waitcnt vmcnt(2)" ::: "memory");
  __builtin_amdgcn_s_barrier();
  __builtin_amdgcn_sched_barrier(0);
  compute(2);
  asm volatile("s_waitcnt vmcnt(0)" ::: "memory");
  __builtin_amdgcn_s_barrier();
  __builtin_amdgcn_sched_barrier(0);
  compute(3);

  const int r0 = by * 128 + wr * 64, c0 = bx * 128 + wc * 32;
#pragma unroll
  for (int ni = 0; ni < 2; ++ni)
#pragma unroll
    for (int mi = 0; mi < 4; ++mi)
#pragma unroll
      for (int r = 0; r < 4; ++r)
        epi_store<EPI>(outp, bias, res, r0 + mi * 16 + l4 * 4 + r,
                       c0 + ni * 16 + l15, N, acc[mi][ni][r]);
}

// ---------------- GEMM 64x64 tile, 256 thr (4 waves 2x2, per-wave 32x32) -----
// 4-buffer pipeline, 3-deep prefetch (stage t+3, counted vmcnt(4)).
template<int EPI>
__global__ __launch_bounds__(256) void gemm64_bf16(
    const bf16_t* __restrict__ A, const bf16_t* __restrict__ Bt,
    const float* __restrict__ bias, const void* __restrict__ res,
    void* __restrict__ outp, int M, int N, int K)
{
  __shared__ alignas(16) bf16_t As[4 * 64 * 32];
  __shared__ alignas(16) bf16_t Bs[4 * 64 * 32];
  const int tid = threadIdx.x, lane = tid & 63, wave = tid >> 6;
  int bx = blockIdx.x, by = blockIdx.y;
  xcd_swizzle(bx, by);
  const int wr = wave >> 1, wc = wave & 1;
  const int l15 = lane & 15, l4 = lane >> 4;

  const int srow = tid >> 2;
  const int soff = swz_slot(srow, tid & 3) * 8;
  const bf16_t* gA = A + (size_t)by * 64 * K + (size_t)srow * K + soff;
  const bf16_t* gB = Bt + (size_t)bx * 64 * K + (size_t)srow * K + soff;
  bf16_t* lA = &As[tid * 8];
  bf16_t* lB = &Bs[tid * 8];

  f32x4 acc[2][2] = {};

  int aoff[2], boff[2];
#pragma unroll
  for (int mi = 0; mi < 2; ++mi) {
    int row = wr * 32 + mi * 16 + l15;
    aoff[mi] = row * 32 + swz_slot(row, l4) * 8;
  }
#pragma unroll
  for (int ni = 0; ni < 2; ++ni) {
    int row = wc * 32 + ni * 16 + l15;
    boff[ni] = row * 32 + swz_slot(row, l4) * 8;
  }

  auto compute = [&](int cur) {   // cur is a literal at every call site
    bf16x8 af[2], bfr[2];
#pragma unroll
    for (int mi = 0; mi < 2; ++mi)
      af[mi] = *(const bf16x8*)&As[cur * 2048 + aoff[mi]];
#pragma unroll
    for (int ni = 0; ni < 2; ++ni)
      bfr[ni] = *(const bf16x8*)&Bs[cur * 2048 + boff[ni]];
#pragma unroll
    for (int mi = 0; mi < 2; ++mi)
#pragma unroll
      for (int ni = 0; ni < 2; ++ni)
        acc[mi][ni] = __builtin_amdgcn_mfma_f32_16x16x32_bf16(af[mi], bfr[ni], acc[mi][ni], 0, 0, 0);
  };

  const int nk = K >> 5;   // divisible by 4 for all shapes used (24, 32, 128)

  // prologue: stage tiles 0,1,2 into buffers 0,1,2
  gload_lds16(gA, lA);             gload_lds16(gB, lB);
  gload_lds16(gA + 32, lA + 2048); gload_lds16(gB + 32, lB + 2048);
  gload_lds16(gA + 64, lA + 2 * 2048); gload_lds16(gB + 64, lB + 2 * 2048);
  asm volatile("s_waitcnt vmcnt(4)" ::: "memory");   // tile 0 landed
  __builtin_amdgcn_s_barrier();
  __builtin_amdgcn_sched_barrier(0);
  gA += 96; gB += 96;   // stage base now at tile 3

  for (int j = 0; j < (nk >> 2) - 1; ++j) {
#pragma unroll
    for (int r = 0; r < 4; ++r) {     // t = 4j + r; compute buf r, stage buf (r+3)&3
      gload_lds16(gA + r * 32, lA + ((r + 3) & 3) * 2048);
      gload_lds16(gB + r * 32, lB + ((r + 3) & 3) * 2048);
      compute(r);
      asm volatile("s_waitcnt vmcnt(4)" ::: "memory");  // next tile ready; 2 iters in flight
      __builtin_amdgcn_s_barrier();
      __builtin_amdgcn_sched_barrier(0);
    }
    gA += 128; gB += 128;
  }
  // last group: t = nk-4 .. nk-1 (buffers 0..3); only t=nk-4 stages (tile nk-1 -> buf 3)
  gload_lds16(gA, lA + 3 * 2048);
  gload_lds16(gB, lB + 3 * 2048);
  compute(0);
  asm volatile("s_waitcnt vmcnt(4)" ::: "memory");
  __builtin_amdgcn_s_barrier();
  __builtin_amdgcn_sched_barrier(0);
  compute(1);
  asm volatile("s_waitcnt vmcnt(2)" ::: "memory");
  __builtin_amdgcn_s_barrier();
  __builtin_amdgcn_sched_barrier(0);
  compute(2);
  asm volatile("s_waitcnt vmcnt(0)" ::: "memory");
  __builtin_amdgcn_s_barrier();
  __builtin_amdgcn_sched_barrier(0);
  compute(3);

  const int r0 = by * 64 + wr * 32, c0 = bx * 64 + wc * 32;
#pragma unroll
  for (int ni = 0; ni < 2; ++ni)
#pragma unroll
    for (int mi = 0; mi < 2; ++mi)
#pragma unroll
      for (int r = 0; r < 4; ++r)
        epi_store<EPI>(outp, bias, res, r0 + mi * 16 + l4 * 4 + r,
                       c0 + ni * 16 + l15, N, acc[mi][ni][r]);
}

// ---------------- V transpose: V[b][key][h*64+d] -> Vt[(b*16+h)][d][key] -----
__global__ void v_transpose(const bf16_t* __restrict__ V, int vs,
                            bf16_t* __restrict__ out, int nk)
{
  __shared__ u16 t[32][33];
  const int z = blockIdx.z;            // b*16 + h
  const int b = z >> 4, h = z & 15;
  const bf16_t* src = V + (size_t)b * nk * vs + h * 64;
  bf16_t* dst = out + (size_t)z * 64 * nk;
  const int k0 = blockIdx.x * 32, d0 = blockIdx.y * 32;
  const int tx = threadIdx.x, ty = threadIdx.y;
#pragma unroll
  for (int i = ty; i < 32; i += 8)
    t[i][tx] = *(const u16*)(src + (size_t)(k0 + i) * vs + d0 + tx);
  __syncthreads();
#pragma unroll
  for (int i = ty; i < 32; i += 8)
    *(u16*)(dst + (size_t)(d0 + i) * nk + k0 + tx) = t[tx][i];
}

// ---------------- Flash attention: 32x32 MFMA, split-K pairs, NO-MAX softmax -
__global__ __launch_bounds__(256, 4) void attn_fwd(
    const bf16_t* __restrict__ Q, int qs,
    const bf16_t* __restrict__ K, int ks,
    const bf16_t* __restrict__ Vt,
    bf16_t* __restrict__ O, int os, int nq, int nk)
{
  __shared__ alignas(16) bf16_t Ks[2][64][72];
  __shared__ alignas(16) bf16_t Vs[2][64][72];   // pre-transposed: [d][key]

  const int tid = threadIdx.x, lane = tid & 63, wv = tid >> 6;
  const int l31 = lane & 31, hi = lane >> 5;
  const int pair = wv >> 1, sK = wv & 1;
  const int h = blockIdx.y, bz = blockIdx.z;
  const size_t qrow0 = (size_t)bz * nq + (size_t)blockIdx.x * 64 + pair * 32;
  const bf16_t* Qb = Q + qrow0 * qs + h * 64;
  const bf16_t* Kb = K + (size_t)bz * nk * ks + h * 64;
  const bf16_t* Vb = Vt + (size_t)(bz * 16 + h) * 64 * nk;   // [d][key]
  bf16_t* Ob = O + qrow0 * os + h * 64;

  // Q as B-operand, pre-scaled by SC2: lane holds Q[q=l31][dk=c*16+hi*8+j]*SC2
  bf16x8 qa[4];
#pragma unroll
  for (int c = 0; c < 4; ++c) {
    bf16x8 t = *(const bf16x8*)(Qb + (size_t)l31 * qs + c * 16 + hi * 8);
#pragma unroll
    for (int j = 0; j < 8; ++j)
      qa[c][j] = (bf16_t)((float)t[j] * ATT_SC2);
  }

  // reg staging: 2x16B per thread per array (row loads; Vt pre-transposed)
  u16x8 kreg[2], vreg[2];
  auto load_tile = [&](int kt) {
#pragma unroll
    for (int i = 0; i < 2; ++i) {
      int lin = i * 256 + tid, row = lin >> 3, col = (lin & 7) * 8;
      kreg[i] = *(const u16x8*)(Kb + (size_t)(kt * 64 + row) * ks + col);
      vreg[i] = *(const u16x8*)(Vb + (size_t)row * nk + kt * 64 + col);
    }
  };
  auto store_tile = [&](int buf) {
#pragma unroll
    for (int i = 0; i < 2; ++i) {
      int lin = i * 256 + tid, row = lin >> 3, col = (lin & 7) * 8;
      *(u16x8*)&Ks[buf][row][col] = kreg[i];
      *(u16x8*)&Vs[buf][row][col] = vreg[i];
    }
  };

  f32x16 acc[2] = {};   // acc[dblk][r] = O[q=(r&3)+8(r>>2)+4hi][d=dblk*32+l31]
  f32x16 lacc = {};     // lacc[r]     = l[q=(r&3)+8(r>>2)+4hi]  (same layout!)

  const bf16_t onev = (bf16_t)1.0f;
  const bf16x8 vones = {onev, onev, onev, onev, onev, onev, onev, onev};

  const int nt = nk >> 6;
  load_tile(0);
  store_tile(0);
  __syncthreads();

  for (int kt = 0; kt < nt; ++kt) {
    const int cur = kt & 1;
    const bool pre = (kt + 1 < nt);
    if (pre) load_tile(kt + 1);   // HBM latency hides under compute

    // S^T over this wave's 32-key half: s[r] = S[key=sK*32+crow(r,hi)][q=l31]*SC2
    f32x16 s = {};
    __builtin_amdgcn_s_setprio(1);
#pragma unroll
    for (int c = 0; c < 4; ++c) {
      bf16x8 kf = *(const bf16x8*)&Ks[cur][sK * 32 + l31][c * 16 + hi * 8];
      s = __builtin_amdgcn_mfma_f32_32x32x16_bf16(kf, qa[c], s, 0, 0, 0);
    }
    __builtin_amdgcn_s_setprio(0);

    // P = 2^s, pack + permlane32_swap into PV A-fragments (no max, no branch)
    u32x4 paw[2];
#pragma unroll
    for (int h2 = 0; h2 < 2; ++h2) {
      u32 a0 = packbf2(exp2f(s[h2 * 8 + 0]), exp2f(s[h2 * 8 + 1]));
      u32 a1 = packbf2(exp2f(s[h2 * 8 + 2]), exp2f(s[h2 * 8 + 3]));
      u32 a2 = packbf2(exp2f(s[h2 * 8 + 4]), exp2f(s[h2 * 8 + 5]));
      u32 a3 = packbf2(exp2f(s[h2 * 8 + 6]), exp2f(s[h2 * 8 + 7]));
      asm volatile("v_permlane32_swap_b32 %0, %1" : "+v"(a0), "+v"(a2));
      asm volatile("v_permlane32_swap_b32 %0, %1" : "+v"(a1), "+v"(a3));
      paw[h2][0] = a0; paw[h2][1] = a1; paw[h2][2] = a2; paw[h2][3] = a3;
    }

    // l += P*ones ; O += P*V   (all on the MFMA pipe)
    __builtin_amdgcn_s_setprio(1);
#pragma unroll
    for (int h2 = 0; h2 < 2; ++h2) {
      union { u32x4 w; bf16x8 v; } pu;
      pu.w = paw[h2];
      lacc = __builtin_amdgcn_mfma_f32_32x32x16_bf16(pu.v, vones, lacc, 0, 0, 0);
#pragma unroll
      for (int dblk = 0; dblk < 2; ++dblk) {
        bf16x8 vb = *(const bf16x8*)&Vs[cur][dblk * 32 + l31][sK * 32 + h2 * 16 + hi * 8];
        acc[dblk] = __builtin_amdgcn_mfma_f32_32x32x16_bf16(pu.v, vb, acc[dblk], 0, 0, 0);
      }
    }
    __builtin_amdgcn_s_setprio(0);

    if (pre) store_tile(cur ^ 1);   // loads have landed by now; write other buf
    __syncthreads();
  }

  // ---- split-K merge: O = (acc0 + acc1) / (l0 + l1); no max combine ----
  float* mb = (float*)&Ks[0][0][0];   // 2 pair x 2 dblk x 16 r x 64 lanes = 16 KB
  float* ml = (float*)&Vs[0][0][0];   // 2 pair x 16 r x 64 lanes = 8 KB
  if (sK == 1) {
#pragma unroll
    for (int dblk = 0; dblk < 2; ++dblk)
#pragma unroll
      for (int r = 0; r < 16; ++r)
        mb[((pair * 2 + dblk) * 16 + r) * 64 + lane] = acc[dblk][r];
#pragma unroll
    for (int r = 0; r < 16; ++r)
      ml[(pair * 16 + r) * 64 + lane] = lacc[r];
  }
  __syncthreads();
  if (sK == 0) {
#pragma unroll
    for (int r = 0; r < 16; ++r) {
      int q = (r & 3) + 8 * (r >> 2) + 4 * hi;
      float inv = 1.f / (lacc[r] + ml[(pair * 16 + r) * 64 + lane]);
#pragma unroll
      for (int dblk = 0; dblk < 2; ++dblk) {
        float o = (acc[dblk][r] + mb[((pair * 2 + dblk) * 16 + r) * 64 + lane]) * inv;
        Ob[(size_t)q * os + dblk * 32 + l31] = (bf16_t)o;
      }
    }
  }
}

// ---------------- LayerNorm fp32-in variant (layer 0), bf16 out, dim=1024 ----
__global__ __launch_bounds__(256) void layernorm_f32(
    const float* __restrict__ x, const float* __restrict__ g, const float* __restrict__ b,
    bf16_t* __restrict__ out)
{
  const int row = blockIdx.x, tid = threadIdx.x;
  const float4 v = ((const float4*)(x + (size_t)row * 1024))[tid];
  float v0 = v.x, v1 = v.y, v2 = v.z, v3 = v.w;
  float s = v0 + v1 + v2 + v3;
  float s2 = v0 * v0 + v1 * v1 + v2 * v2 + v3 * v3;
#pragma unroll
  for (int off = 32; off > 0; off >>= 1) {
    s += __shfl_down(s, off);
    s2 += __shfl_down(s2, off);
  }
  __shared__ float ps[4], ps2[4];
  const int lane = tid & 63, wave = tid >> 6;
  if (lane == 0) { ps[wave] = s; ps2[wave] = s2; }
  __syncthreads();
  s = ps[0] + ps[1] + ps[2] + ps[3];
  s2 = ps2[0] + ps2[1] + ps2[2] + ps2[3];
  const float mu = s * (1.f / 1024.f);
  const float var = s2 * (1.f / 1024.f) - mu * mu;
  const float rstd = rsqrtf(var + 1e-5f);
  const float4 gv = ((const float4*)g)[tid];
  const float4 bv = ((const float4*)b)[tid];
  bf16x4 o;
  o[0] = (bf16_t)((v0 - mu) * rstd * gv.x + bv.x);
  o[1] = (bf16_t)((v1 - mu) * rstd * gv.y + bv.y);
  o[2] = (bf16_t)((v2 - mu) * rstd * gv.z + bv.z);
  o[3] = (bf16_t)((v3 - mu) * rstd * gv.w + bv.w);
  *(bf16x4*)(out + (size_t)row * 1024 + tid * 4) = o;
}

// ---------------- LayerNorm bf16-in variant (residual stream), dim=1024 ------
__global__ __launch_bounds__(256) void layernorm_b16(
    const bf16_t* __restrict__ x, const float* __restrict__ g, const float* __restrict__ b,
    bf16_t* __restrict__ out)
{
  const int row = blockIdx.x, tid = threadIdx.x;
  const bf16x4 xv = *(const bf16x4*)(x + (size_t)row * 1024 + tid * 4);
  float v0 = (float)xv[0], v1 = (float)xv[1], v2 = (float)xv[2], v3 = (float)xv[3];
  float s = v0 + v1 + v2 + v3;
  float s2 = v0 * v0 + v1 * v1 + v2 * v2 + v3 * v3;
#pragma unroll
  for (int off = 32; off > 0; off >>= 1) {
    s += __shfl_down(s, off);
    s2 += __shfl_down(s2, off);
  }
  __shared__ float ps[4], ps2[4];
  const int lane = tid & 63, wave = tid >> 6;
  if (lane == 0) { ps[wave] = s; ps2[wave] = s2; }
  __syncthreads();
  s = ps[0] + ps[1] + ps[2] + ps[3];
  s2 = ps2[0] + ps2[1] + ps2[2] + ps2[3];
  const float mu = s * (1.f / 1024.f);
  const float var = s2 * (1.f / 1024.f) - mu * mu;
  const float rstd = rsqrtf(var + 1e-5f);
  const float4 gv = ((const float4*)g)[tid];
  const float4 bv = ((const float4*)b)[tid];
  bf16x4 o;
  o[0] = (bf16_t)((v0 - mu) * rstd * gv.x + bv.x);
  o[1] = (bf16_t)((v1 - mu) * rstd * gv.y + bv.y);
  o[2] = (bf16_t)((v2 - mu) * rstd * gv.z + bv.z);
  o[3] = (bf16_t)((v3 - mu) * rstd * gv.w + bv.w);
  *(bf16x4*)(out + (size_t)row * 1024 + tid * 4) = o;
}

// ---------------- weight transpose fp32[K,N] -> bf16[N,K], per-layer in grid.z ----------------
__global__ void transpose_to_bf16(const float* __restrict__ src, bf16_t* __restrict__ dst, int K, int N)
{
  __shared__ float tile[32][33];
  const size_t loff = (size_t)blockIdx.z * K * N;
  src += loff; dst += loff;
  const int k0 = blockIdx.y * 32, n0 = blockIdx.x * 32;
  const int tx = threadIdx.x, ty = threadIdx.y;
#pragma unroll
  for (int i = ty; i < 32; i += 8)
    tile[i][tx] = src[(size_t)(k0 + i) * N + n0 + tx];
  __syncthreads();
#pragma unroll
  for (int i = ty; i < 32; i += 8)
    dst[(size_t)(n0 + i) * K + k0 + tx] = (bf16_t)tile[tx][i];
}

__global__ void f32_to_bf16(const float* __restrict__ src, bf16_t* __restrict__ dst, int n4)
{
  int i = blockIdx.x * blockDim.x + threadIdx.x;
  if (i < n4) {
    float4 v = ((const float4*)src)[i];
    bf16x4 o;
    o[0] = (bf16_t)v.x; o[1] = (bf16_t)v.y; o[2] = (bf16_t)v.z; o[3] = (bf16_t)v.w;
    ((bf16x4*)dst)[i] = o;
  }
}

extern "C" void kernel_launch(void* const* d_in, const int* in_sizes, int n_in,
                              void* d_out, int out_size, void* d_ws, size_t ws_size,
                              hipStream_t stream)
{
  const float* x      = (const float*)d_in[0];
  const float* ctx    = (const float*)d_in[1];
  const float* ln1_g  = (const float*)d_in[2];
  const float* ln1_b  = (const float*)d_in[3];
  const float* w_qkv  = (const float*)d_in[4];
  const float* w_sa_o = (const float*)d_in[5];
  const float* b_sa_o = (const float*)d_in[6];
  const float* ln2_g  = (const float*)d_in[7];
  const float* ln2_b  = (const float*)d_in[8];
  const float* w_q    = (const float*)d_in[9];
  const float* w_kv   = (const float*)d_in[10];
  const float* w_ca_o = (const float*)d_in[11];
  const float* b_ca_o = (const float*)d_in[12];
  const float* ln3_g  = (const float*)d_in[13];
  const float* ln3_b  = (const float*)d_in[14];
  const float* w_ff1  = (const float*)d_in[15];
  const float* b_ff1  = (const float*)d_in[16];
  const float* w_ff2  = (const float*)d_in[17];
  const float* b_ff2  = (const float*)d_in[18];

  char* p = (char*)d_ws;
  auto alloc = [&](size_t bytes) { char* r = p; p += (bytes + 255) & ~(size_t)255; return r; };
  bf16_t* wqkv_t = (bf16_t*)alloc((size_t)NDEPTH * 3072 * 1024 * 2);
  bf16_t* wsao_t = (bf16_t*)alloc((size_t)NDEPTH * 1024 * 1024 * 2);
  bf16_t* wq_t   = (bf16_t*)alloc((size_t)NDEPTH * 1024 * 1024 * 2);
  bf16_t* wkv_t  = (bf16_t*)alloc((size_t)NDEPTH * 2048 * 768 * 2);
  bf16_t* wcao_t = (bf16_t*)alloc((size_t)NDEPTH * 1024 * 1024 * 2);
  bf16_t* wff1_t = (bf16_t*)alloc((size_t)NDEPTH * 4096 * 1024 * 2);
  bf16_t* wff2_t = (bf16_t*)alloc((size_t)NDEPTH * 1024 * 4096 * 2);
  bf16_t* ctxb   = (bf16_t*)alloc((size_t)NCTX * CTXD * 2);
  bf16_t* xbuf   = (bf16_t*)alloc((size_t)NTOK * DIM * 2);    // bf16 residual stream
  bf16_t* lnbuf  = (bf16_t*)alloc((size_t)NTOK * DIM * 2);    // also attention out
  bf16_t* bigbuf = (bf16_t*)alloc((size_t)NTOK * 4096 * 2);   // qkv / ff1 out
  bf16_t* qbuf   = (bf16_t*)alloc((size_t)NTOK * DIM * 2);
  bf16_t* kvbuf  = (bf16_t*)alloc((size_t)NCTX * 2048 * 2);
  bf16_t* vtbuf  = (bf16_t*)alloc((size_t)32 * 64 * 2048 * 2);  // self V^T [b*h][d][key]
  bf16_t* vtcbuf = (bf16_t*)alloc((size_t)32 * 64 * 1024 * 2);  // cross V^T
  if ((size_t)(p - (char*)d_ws) > ws_size) return;  // workspace too small: fail loudly

  dim3 tb(32, 8);
  transpose_to_bf16<<<dim3(3072 / 32, 1024 / 32, NDEPTH), tb, 0, stream>>>(w_qkv, wqkv_t, 1024, 3072);
  transpose_to_bf16<<<dim3(1024 / 32, 1024 / 32, NDEPTH), tb, 0, stream>>>(w_sa_o, wsao_t, 1024, 1024);
  transpose_to_bf16<<<dim3(1024 / 32, 1024 / 32, NDEPTH), tb, 0, stream>>>(w_q, wq_t, 1024, 1024);
  transpose_to_bf16<<<dim3(2048 / 32, 768 / 32, NDEPTH), tb, 0, stream>>>(w_kv, wkv_t, 768, 2048);
  transpose_to_bf16<<<dim3(1024 / 32, 1024 / 32, NDEPTH), tb, 0, stream>>>(w_ca_o, wcao_t, 1024, 1024);
  transpose_to_bf16<<<dim3(4096 / 32, 1024 / 32, NDEPTH), tb, 0, stream>>>(w_ff1, wff1_t, 1024, 4096);
  transpose_to_bf16<<<dim3(1024 / 32, 4096 / 32, NDEPTH), tb, 0, stream>>>(w_ff2, wff2_t, 4096, 1024);
  f32_to_bf16<<<(NCTX * CTXD / 4 + 255) / 256, 256, 0, stream>>>(ctx, ctxb, NCTX * CTXD / 4);

  for (int i = 0; i < NDEPTH; ++i) {
    // ---- self-attention ----
    if (i == 0)
      layernorm_f32<<<NTOK, 256, 0, stream>>>(x, ln1_g, ln1_b, lnbuf);
    else
      layernorm_b16<<<NTOK, 256, 0, stream>>>(xbuf, ln1_g + i * DIM, ln1_b + i * DIM, lnbuf);
    gemm_bf16<0><<<dim3(3072 / 128, NTOK / 128), 512, 0, stream>>>(
        lnbuf, wqkv_t + (size_t)i * 3072 * 1024, nullptr, nullptr, bigbuf, NTOK, 3072, 1024);
    v_transpose<<<dim3(2048 / 32, 2, 32), tb, 0, stream>>>(bigbuf + 2048, 3072, vtbuf, 2048);
    attn_fwd<<<dim3(2048 / 64, NHEADS, 2), 256, 0, stream>>>(
        bigbuf, 3072, bigbuf + 1024, 3072, vtbuf, lnbuf, 1024, 2048, 2048);
    if (i == 0)
      gemm64_bf16<4><<<dim3(1024 / 64, NTOK / 64), 256, 0, stream>>>(
          lnbuf, wsao_t, b_sa_o, x, xbuf, NTOK, 1024, 1024);
    else
      gemm64_bf16<3><<<dim3(1024 / 64, NTOK / 64), 256, 0, stream>>>(
          lnbuf, wsao_t + (size_t)i * 1024 * 1024, b_sa_o + i * DIM, xbuf, xbuf, NTOK, 1024, 1024);
    // ---- cross-attention ----
    layernorm_b16<<<NTOK, 256, 0, stream>>>(xbuf, ln2_g + i * DIM, ln2_b + i * DIM, lnbuf);
    gemm64_bf16<0><<<dim3(1024 / 64, NTOK / 64), 256, 0, stream>>>(
        lnbuf, wq_t + (size_t)i * 1024 * 1024, nullptr, nullptr, qbuf, NTOK, 1024, 1024);
    gemm64_bf16<0><<<dim3(2048 / 64, NCTX / 64), 256, 0, stream>>>(
        ctxb, wkv_t + (size_t)i * 2048 * 768, nullptr, nullptr, kvbuf, NCTX, 2048, 768);
    v_transpose<<<dim3(1024 / 32, 2, 32), tb, 0, stream>>>(kvbuf + 1024, 2048, vtcbuf, 1024);
    attn_fwd<<<dim3(2048 / 64, NHEADS, 2), 256, 0, stream>>>(
        qbuf, 1024, kvbuf, 2048, vtcbuf, lnbuf, 1024, 2048, 1024);
    gemm64_bf16<3><<<dim3(1024 / 64, NTOK / 64), 256, 0, stream>>>(
        lnbuf, wcao_t + (size_t)i * 1024 * 1024, b_ca_o + i * DIM, xbuf, xbuf, NTOK, 1024, 1024);
    // ---- feed-forward ----
    layernorm_b16<<<NTOK, 256, 0, stream>>>(xbuf, ln3_g + i * DIM, ln3_b + i * DIM, lnbuf);
    gemm_bf16<2><<<dim3(4096 / 128, NTOK / 128), 512, 0, stream>>>(
        lnbuf, wff1_t + (size_t)i * 4096 * 1024, b_ff1 + i * MLP_DIM, nullptr, bigbuf, NTOK, 4096, 1024);
    if (i == NDEPTH - 1)
      gemm64_bf16<5><<<dim3(1024 / 64, NTOK / 64), 256, 0, stream>>>(
          bigbuf, wff2_t + (size_t)i * 1024 * 4096, b_ff2 + i * DIM, xbuf, d_out, NTOK, 1024, 4096);
    else
      gemm64_bf16<3><<<dim3(1024 / 64, NTOK / 64), 256, 0, stream>>>(
          bigbuf, wff2_t + (size_t)i * 1024 * 4096, b_ff2 + i * DIM, xbuf, xbuf, NTOK, 1024, 4096);
  }
}

// Round 19
// 1547.642 us; speedup vs baseline: 1.0107x; 1.0107x over previous
//
#include <hip/hip_runtime.h>
#include <hip/hip_bf16.h>
#include <math.h>

typedef __bf16 bf16_t;
typedef __bf16 bf16x8 __attribute__((ext_vector_type(8)));
typedef __bf16 bf16x4 __attribute__((ext_vector_type(4)));
typedef float f32x4 __attribute__((ext_vector_type(4)));
typedef float f32x16 __attribute__((ext_vector_type(16)));
typedef unsigned short u16;
typedef unsigned int u32;
typedef u16 u16x8 __attribute__((ext_vector_type(8)));
typedef u32 u32x4 __attribute__((ext_vector_type(4)));

#define NDEPTH 4
#define DIM 1024
#define NHEADS 16
#define MLP_DIM 4096
#define CTXD 768
#define NTOK 4096
#define NCTX 2048
// softmax in exp2 domain: p = 2^(s*SC2), SC2 = 0.125 * log2(e), folded into Q
#define ATT_SC2 0.18033688011112042f

__device__ inline void gload_lds16(const void* g, void* l) {
  __builtin_amdgcn_global_load_lds(
      (const __attribute__((address_space(1))) void*)g,
      (__attribute__((address_space(3))) void*)l, 16, 0, 0);
}

__device__ inline u32 packbf2(float a, float b) {
  union { bf16_t h[2]; u32 w; } u;
  u.h[0] = (bf16_t)a; u.h[1] = (bf16_t)b;
  return u.w;
}

// bijective XCD swizzle (valid when nwg % 8 == 0; all launches here comply)
__device__ inline void xcd_swizzle(int& bx, int& by) {
  const int gx = gridDim.x, nwg = gx * gridDim.y;
  int id = by * gx + bx;
  id = (id & 7) * (nwg >> 3) + (id >> 3);
  bx = id % gx; by = id / gx;
}

// GELU, tanh form via exp2+rcp: 0.5v(1+tanh(c1(v+c2 v^3))) = v*(1 - 1/(e^{2y}+1)).
__device__ inline float gelu_fast(float v) {
  float y = 0.79788456f * (v + 0.044715f * v * v * v);
  float t = exp2f(y * 2.885390082f);           // e^{2y}
  return v * (1.f - 1.f / (t + 1.f));
}

// Epilogues. Residual stream lives in BF16:
//   0: bf16 out            2: bias+GELU, bf16 out
//   3: bias + bf16 res -> bf16 out        (steady-state residual)
//   4: bias + fp32 res -> bf16 out        (layer-0 sa_o, res = input x)
//   5: bias + bf16 res -> fp32 out        (final ff2 -> d_out)
template<int EPI>
__device__ inline void epi_store(void* outp, const float* bias, const void* resv,
                                 int row, int col, int N, float v) {
  size_t idx = (size_t)row * N + col;
  if (EPI == 0) {
    ((bf16_t*)outp)[idx] = (bf16_t)v;
  } else if (EPI == 2) {
    ((bf16_t*)outp)[idx] = (bf16_t)gelu_fast(v + bias[col]);
  } else if (EPI == 3) {
    float r = (float)((const bf16_t*)resv)[idx];
    ((bf16_t*)outp)[idx] = (bf16_t)(v + bias[col] + r);
  } else if (EPI == 4) {
    float r = ((const float*)resv)[idx];
    ((bf16_t*)outp)[idx] = (bf16_t)(v + bias[col] + r);
  } else if (EPI == 5) {
    float r = (float)((const bf16_t*)resv)[idx];
    ((float*)outp)[idx] = v + bias[col] + r;
  }
}

// T2 bank-conflict swizzle for [rows][32bf16] GEMM LDS tiles (2-bit slot),
// applied identically on the staging SOURCE column and every read (involution).
__device__ inline int swz_slot(int row, int slot) { return slot ^ ((row >> 1) & 3); }

// ---------------- GEMM 128x128 tile, 512 thr (8 waves 2x4, per-wave 64x32) ----
// 3-buffer pipeline (48 KB LDS -> 3 blocks/CU), groups of 3 with compile-time
// buffer index. For this kernel occupancy beats pipeline depth (r18 measured:
// 4-buffer/64KB was +16us); gemm64 is the opposite (depth wins there).
template<int EPI>
__global__ __launch_bounds__(512) void gemm_bf16(
    const bf16_t* __restrict__ A, const bf16_t* __restrict__ Bt,
    const float* __restrict__ bias, const void* __restrict__ res,
    void* __restrict__ outp, int M, int N, int K)
{
  __shared__ alignas(16) bf16_t As[3 * 128 * 32];
  __shared__ alignas(16) bf16_t Bs[3 * 128 * 32];
  const int tid = threadIdx.x, lane = tid & 63, wave = tid >> 6;
  int bx = blockIdx.x, by = blockIdx.y;
  xcd_swizzle(bx, by);
  const int wr = wave >> 2, wc = wave & 3;
  const int l15 = lane & 15, l4 = lane >> 4;

  const int srow = tid >> 2;
  const int soff = swz_slot(srow, tid & 3) * 8;
  const bf16_t* gA = A + (size_t)by * 128 * K + (size_t)srow * K + soff;
  const bf16_t* gB = Bt + (size_t)bx * 128 * K + (size_t)srow * K + soff;
  bf16_t* lA = &As[tid * 8];
  bf16_t* lB = &Bs[tid * 8];

  f32x4 acc[4][2] = {};

  int aoff[4], boff[2];
#pragma unroll
  for (int mi = 0; mi < 4; ++mi) {
    int row = wr * 64 + mi * 16 + l15;
    aoff[mi] = row * 32 + swz_slot(row, l4) * 8;
  }
#pragma unroll
  for (int ni = 0; ni < 2; ++ni) {
    int row = wc * 32 + ni * 16 + l15;
    boff[ni] = row * 32 + swz_slot(row, l4) * 8;
  }

  auto compute = [&](int cur) {   // cur is a literal at every call site
    bf16x8 af[4], bfr[2];
#pragma unroll
    for (int mi = 0; mi < 4; ++mi)
      af[mi] = *(const bf16x8*)&As[cur * 4096 + aoff[mi]];
#pragma unroll
    for (int ni = 0; ni < 2; ++ni)
      bfr[ni] = *(const bf16x8*)&Bs[cur * 4096 + boff[ni]];
#pragma unroll
    for (int mi = 0; mi < 4; ++mi)
#pragma unroll
      for (int ni = 0; ni < 2; ++ni)
        acc[mi][ni] = __builtin_amdgcn_mfma_f32_16x16x32_bf16(af[mi], bfr[ni], acc[mi][ni], 0, 0, 0);
  };

  const int nk = K >> 5;   // == 32 for all gemm_bf16 launches (K=1024)

  gload_lds16(gA, lA);            gload_lds16(gB, lB);
  gload_lds16(gA + 32, lA + 4096); gload_lds16(gB + 32, lB + 4096);
  asm volatile("s_waitcnt vmcnt(2)" ::: "memory");
  __builtin_amdgcn_s_barrier();
  __builtin_amdgcn_sched_barrier(0);
  gA += 64; gB += 64;   // stage base for t+2

  const int ngroups = (nk - 2) / 3;   // nk ≡ 2 (mod 3)
  for (int j = 0; j < ngroups; ++j) {
#pragma unroll
    for (int r = 0; r < 3; ++r) {     // t = 3j + r; buffers cycle r, stage (r+2)%3
      gload_lds16(gA + r * 32, lA + ((r + 2) % 3) * 4096);
      gload_lds16(gB + r * 32, lB + ((r + 2) % 3) * 4096);
      compute(r);
      asm volatile("s_waitcnt vmcnt(2)" ::: "memory");
      __builtin_amdgcn_s_barrier();
      __builtin_amdgcn_sched_barrier(0);
    }
    gA += 96; gB += 96;
  }
  // tail: t = nk-2 (cur 0), nk-1 (cur 1)
  compute(0);
  asm volatile("s_waitcnt vmcnt(0)" ::: "memory");
  __builtin_amdgcn_s_barrier();
  __builtin_amdgcn_sched_barrier(0);
  compute(1);

  const int r0 = by * 128 + wr * 64, c0 = bx * 128 + wc * 32;
#pragma unroll
  for (int ni = 0; ni < 2; ++ni)
#pragma unroll
    for (int mi = 0; mi < 4; ++mi)
#pragma unroll
      for (int r = 0; r < 4; ++r)
        epi_store<EPI>(outp, bias, res, r0 + mi * 16 + l4 * 4 + r,
                       c0 + ni * 16 + l15, N, acc[mi][ni][r]);
}

// ---------------- GEMM 64x64 tile, 256 thr (4 waves 2x2, per-wave 32x32) -----
// 4-buffer pipeline, 3-deep prefetch (stage t+3, counted vmcnt(4)).
template<int EPI>
__global__ __launch_bounds__(256) void gemm64_bf16(
    const bf16_t* __restrict__ A, const bf16_t* __restrict__ Bt,
    const float* __restrict__ bias, const void* __restrict__ res,
    void* __restrict__ outp, int M, int N, int K)
{
  __shared__ alignas(16) bf16_t As[4 * 64 * 32];
  __shared__ alignas(16) bf16_t Bs[4 * 64 * 32];
  const int tid = threadIdx.x, lane = tid & 63, wave = tid >> 6;
  int bx = blockIdx.x, by = blockIdx.y;
  xcd_swizzle(bx, by);
  const int wr = wave >> 1, wc = wave & 1;
  const int l15 = lane & 15, l4 = lane >> 4;

  const int srow = tid >> 2;
  const int soff = swz_slot(srow, tid & 3) * 8;
  const bf16_t* gA = A + (size_t)by * 64 * K + (size_t)srow * K + soff;
  const bf16_t* gB = Bt + (size_t)bx * 64 * K + (size_t)srow * K + soff;
  bf16_t* lA = &As[tid * 8];
  bf16_t* lB = &Bs[tid * 8];

  f32x4 acc[2][2] = {};

  int aoff[2], boff[2];
#pragma unroll
  for (int mi = 0; mi < 2; ++mi) {
    int row = wr * 32 + mi * 16 + l15;
    aoff[mi] = row * 32 + swz_slot(row, l4) * 8;
  }
#pragma unroll
  for (int ni = 0; ni < 2; ++ni) {
    int row = wc * 32 + ni * 16 + l15;
    boff[ni] = row * 32 + swz_slot(row, l4) * 8;
  }

  auto compute = [&](int cur) {   // cur is a literal at every call site
    bf16x8 af[2], bfr[2];
#pragma unroll
    for (int mi = 0; mi < 2; ++mi)
      af[mi] = *(const bf16x8*)&As[cur * 2048 + aoff[mi]];
#pragma unroll
    for (int ni = 0; ni < 2; ++ni)
      bfr[ni] = *(const bf16x8*)&Bs[cur * 2048 + boff[ni]];
#pragma unroll
    for (int mi = 0; mi < 2; ++mi)
#pragma unroll
      for (int ni = 0; ni < 2; ++ni)
        acc[mi][ni] = __builtin_amdgcn_mfma_f32_16x16x32_bf16(af[mi], bfr[ni], acc[mi][ni], 0, 0, 0);
  };

  const int nk = K >> 5;   // divisible by 4 for all shapes used (24, 32, 128)

  // prologue: stage tiles 0,1,2 into buffers 0,1,2
  gload_lds16(gA, lA);             gload_lds16(gB, lB);
  gload_lds16(gA + 32, lA + 2048); gload_lds16(gB + 32, lB + 2048);
  gload_lds16(gA + 64, lA + 2 * 2048); gload_lds16(gB + 64, lB + 2 * 2048);
  asm volatile("s_waitcnt vmcnt(4)" ::: "memory");   // tile 0 landed
  __builtin_amdgcn_s_barrier();
  __builtin_amdgcn_sched_barrier(0);
  gA += 96; gB += 96;   // stage base now at tile 3

  for (int j = 0; j < (nk >> 2) - 1; ++j) {
#pragma unroll
    for (int r = 0; r < 4; ++r) {     // t = 4j + r; compute buf r, stage buf (r+3)&3
      gload_lds16(gA + r * 32, lA + ((r + 3) & 3) * 2048);
      gload_lds16(gB + r * 32, lB + ((r + 3) & 3) * 2048);
      compute(r);
      asm volatile("s_waitcnt vmcnt(4)" ::: "memory");  // next tile ready; 2 iters in flight
      __builtin_amdgcn_s_barrier();
      __builtin_amdgcn_sched_barrier(0);
    }
    gA += 128; gB += 128;
  }
  // last group: t = nk-4 .. nk-1 (buffers 0..3); only t=nk-4 stages (tile nk-1 -> buf 3)
  gload_lds16(gA, lA + 3 * 2048);
  gload_lds16(gB, lB + 3 * 2048);
  compute(0);
  asm volatile("s_waitcnt vmcnt(4)" ::: "memory");
  __builtin_amdgcn_s_barrier();
  __builtin_amdgcn_sched_barrier(0);
  compute(1);
  asm volatile("s_waitcnt vmcnt(2)" ::: "memory");
  __builtin_amdgcn_s_barrier();
  __builtin_amdgcn_sched_barrier(0);
  compute(2);
  asm volatile("s_waitcnt vmcnt(0)" ::: "memory");
  __builtin_amdgcn_s_barrier();
  __builtin_amdgcn_sched_barrier(0);
  compute(3);

  const int r0 = by * 64 + wr * 32, c0 = bx * 64 + wc * 32;
#pragma unroll
  for (int ni = 0; ni < 2; ++ni)
#pragma unroll
    for (int mi = 0; mi < 2; ++mi)
#pragma unroll
      for (int r = 0; r < 4; ++r)
        epi_store<EPI>(outp, bias, res, r0 + mi * 16 + l4 * 4 + r,
                       c0 + ni * 16 + l15, N, acc[mi][ni][r]);
}

// ---------------- V transpose: V[b][key][h*64+d] -> Vt[(b*16+h)][d][key] -----
__global__ void v_transpose(const bf16_t* __restrict__ V, int vs,
                            bf16_t* __restrict__ out, int nk)
{
  __shared__ u16 t[32][33];
  const int z = blockIdx.z;            // b*16 + h
  const int b = z >> 4, h = z & 15;
  const bf16_t* src = V + (size_t)b * nk * vs + h * 64;
  bf16_t* dst = out + (size_t)z * 64 * nk;
  const int k0 = blockIdx.x * 32, d0 = blockIdx.y * 32;
  const int tx = threadIdx.x, ty = threadIdx.y;
#pragma unroll
  for (int i = ty; i < 32; i += 8)
    t[i][tx] = *(const u16*)(src + (size_t)(k0 + i) * vs + d0 + tx);
  __syncthreads();
#pragma unroll
  for (int i = ty; i < 32; i += 8)
    *(u16*)(dst + (size_t)(d0 + i) * nk + k0 + tx) = t[tx][i];
}

// ---------------- Flash attention: 32x32 MFMA, split-K pairs, NO-MAX softmax -
__global__ __launch_bounds__(256, 4) void attn_fwd(
    const bf16_t* __restrict__ Q, int qs,
    const bf16_t* __restrict__ K, int ks,
    const bf16_t* __restrict__ Vt,
    bf16_t* __restrict__ O, int os, int nq, int nk)
{
  __shared__ alignas(16) bf16_t Ks[2][64][72];
  __shared__ alignas(16) bf16_t Vs[2][64][72];   // pre-transposed: [d][key]

  const int tid = threadIdx.x, lane = tid & 63, wv = tid >> 6;
  const int l31 = lane & 31, hi = lane >> 5;
  const int pair = wv >> 1, sK = wv & 1;
  const int h = blockIdx.y, bz = blockIdx.z;
  const size_t qrow0 = (size_t)bz * nq + (size_t)blockIdx.x * 64 + pair * 32;
  const bf16_t* Qb = Q + qrow0 * qs + h * 64;
  const bf16_t* Kb = K + (size_t)bz * nk * ks + h * 64;
  const bf16_t* Vb = Vt + (size_t)(bz * 16 + h) * 64 * nk;   // [d][key]
  bf16_t* Ob = O + qrow0 * os + h * 64;

  // Q as B-operand, pre-scaled by SC2: lane holds Q[q=l31][dk=c*16+hi*8+j]*SC2
  bf16x8 qa[4];
#pragma unroll
  for (int c = 0; c < 4; ++c) {
    bf16x8 t = *(const bf16x8*)(Qb + (size_t)l31 * qs + c * 16 + hi * 8);
#pragma unroll
    for (int j = 0; j < 8; ++j)
      qa[c][j] = (bf16_t)((float)t[j] * ATT_SC2);
  }

  // reg staging: 2x16B per thread per array (row loads; Vt pre-transposed)
  u16x8 kreg[2], vreg[2];
  auto load_tile = [&](int kt) {
#pragma unroll
    for (int i = 0; i < 2; ++i) {
      int lin = i * 256 + tid, row = lin >> 3, col = (lin & 7) * 8;
      kreg[i] = *(const u16x8*)(Kb + (size_t)(kt * 64 + row) * ks + col);
      vreg[i] = *(const u16x8*)(Vb + (size_t)row * nk + kt * 64 + col);
    }
  };
  auto store_tile = [&](int buf) {
#pragma unroll
    for (int i = 0; i < 2; ++i) {
      int lin = i * 256 + tid, row = lin >> 3, col = (lin & 7) * 8;
      *(u16x8*)&Ks[buf][row][col] = kreg[i];
      *(u16x8*)&Vs[buf][row][col] = vreg[i];
    }
  };

  f32x16 acc[2] = {};   // acc[dblk][r] = O[q=(r&3)+8(r>>2)+4hi][d=dblk*32+l31]
  f32x16 lacc = {};     // lacc[r]     = l[q=(r&3)+8(r>>2)+4hi]  (same layout!)

  const bf16_t onev = (bf16_t)1.0f;
  const bf16x8 vones = {onev, onev, onev, onev, onev, onev, onev, onev};

  const int nt = nk >> 6;
  load_tile(0);
  store_tile(0);
  __syncthreads();

  for (int kt = 0; kt < nt; ++kt) {
    const int cur = kt & 1;
    const bool pre = (kt + 1 < nt);
    if (pre) load_tile(kt + 1);   // HBM latency hides under compute

    // S^T over this wave's 32-key half: s[r] = S[key=sK*32+crow(r,hi)][q=l31]*SC2
    f32x16 s = {};
    __builtin_amdgcn_s_setprio(1);
#pragma unroll
    for (int c = 0; c < 4; ++c) {
      bf16x8 kf = *(const bf16x8*)&Ks[cur][sK * 32 + l31][c * 16 + hi * 8];
      s = __builtin_amdgcn_mfma_f32_32x32x16_bf16(kf, qa[c], s, 0, 0, 0);
    }
    __builtin_amdgcn_s_setprio(0);

    // P = 2^s, pack + permlane32_swap into PV A-fragments (no max, no branch)
    u32x4 paw[2];
#pragma unroll
    for (int h2 = 0; h2 < 2; ++h2) {
      u32 a0 = packbf2(exp2f(s[h2 * 8 + 0]), exp2f(s[h2 * 8 + 1]));
      u32 a1 = packbf2(exp2f(s[h2 * 8 + 2]), exp2f(s[h2 * 8 + 3]));
      u32 a2 = packbf2(exp2f(s[h2 * 8 + 4]), exp2f(s[h2 * 8 + 5]));
      u32 a3 = packbf2(exp2f(s[h2 * 8 + 6]), exp2f(s[h2 * 8 + 7]));
      asm volatile("v_permlane32_swap_b32 %0, %1" : "+v"(a0), "+v"(a2));
      asm volatile("v_permlane32_swap_b32 %0, %1" : "+v"(a1), "+v"(a3));
      paw[h2][0] = a0; paw[h2][1] = a1; paw[h2][2] = a2; paw[h2][3] = a3;
    }

    // l += P*ones ; O += P*V   (all on the MFMA pipe)
    __builtin_amdgcn_s_setprio(1);
#pragma unroll
    for (int h2 = 0; h2 < 2; ++h2) {
      union { u32x4 w; bf16x8 v; } pu;
      pu.w = paw[h2];
      lacc = __builtin_amdgcn_mfma_f32_32x32x16_bf16(pu.v, vones, lacc, 0, 0, 0);
#pragma unroll
      for (int dblk = 0; dblk < 2; ++dblk) {
        bf16x8 vb = *(const bf16x8*)&Vs[cur][dblk * 32 + l31][sK * 32 + h2 * 16 + hi * 8];
        acc[dblk] = __builtin_amdgcn_mfma_f32_32x32x16_bf16(pu.v, vb, acc[dblk], 0, 0, 0);
      }
    }
    __builtin_amdgcn_s_setprio(0);

    if (pre) store_tile(cur ^ 1);   // loads have landed by now; write other buf
    __syncthreads();
  }

  // ---- split-K merge: O = (acc0 + acc1) / (l0 + l1); no max combine ----
  float* mb = (float*)&Ks[0][0][0];   // 2 pair x 2 dblk x 16 r x 64 lanes = 16 KB
  float* ml = (float*)&Vs[0][0][0];   // 2 pair x 16 r x 64 lanes = 8 KB
  if (sK == 1) {
#pragma unroll
    for (int dblk = 0; dblk < 2; ++dblk)
#pragma unroll
      for (int r = 0; r < 16; ++r)
        mb[((pair * 2 + dblk) * 16 + r) * 64 + lane] = acc[dblk][r];
#pragma unroll
    for (int r = 0; r < 16; ++r)
      ml[(pair * 16 + r) * 64 + lane] = lacc[r];
  }
  __syncthreads();
  if (sK == 0) {
#pragma unroll
    for (int r = 0; r < 16; ++r) {
      int q = (r & 3) + 8 * (r >> 2) + 4 * hi;
      float inv = 1.f / (lacc[r] + ml[(pair * 16 + r) * 64 + lane]);
#pragma unroll
      for (int dblk = 0; dblk < 2; ++dblk) {
        float o = (acc[dblk][r] + mb[((pair * 2 + dblk) * 16 + r) * 64 + lane]) * inv;
        Ob[(size_t)q * os + dblk * 32 + l31] = (bf16_t)o;
      }
    }
  }
}

// ---------------- LayerNorm fp32-in variant (layer 0), bf16 out, dim=1024 ----
__global__ __launch_bounds__(256) void layernorm_f32(
    const float* __restrict__ x, const float* __restrict__ g, const float* __restrict__ b,
    bf16_t* __restrict__ out)
{
  const int row = blockIdx.x, tid = threadIdx.x;
  const float4 v = ((const float4*)(x + (size_t)row * 1024))[tid];
  float v0 = v.x, v1 = v.y, v2 = v.z, v3 = v.w;
  float s = v0 + v1 + v2 + v3;
  float s2 = v0 * v0 + v1 * v1 + v2 * v2 + v3 * v3;
#pragma unroll
  for (int off = 32; off > 0; off >>= 1) {
    s += __shfl_down(s, off);
    s2 += __shfl_down(s2, off);
  }
  __shared__ float ps[4], ps2[4];
  const int lane = tid & 63, wave = tid >> 6;
  if (lane == 0) { ps[wave] = s; ps2[wave] = s2; }
  __syncthreads();
  s = ps[0] + ps[1] + ps[2] + ps[3];
  s2 = ps2[0] + ps2[1] + ps2[2] + ps2[3];
  const float mu = s * (1.f / 1024.f);
  const float var = s2 * (1.f / 1024.f) - mu * mu;
  const float rstd = rsqrtf(var + 1e-5f);
  const float4 gv = ((const float4*)g)[tid];
  const float4 bv = ((const float4*)b)[tid];
  bf16x4 o;
  o[0] = (bf16_t)((v0 - mu) * rstd * gv.x + bv.x);
  o[1] = (bf16_t)((v1 - mu) * rstd * gv.y + bv.y);
  o[2] = (bf16_t)((v2 - mu) * rstd * gv.z + bv.z);
  o[3] = (bf16_t)((v3 - mu) * rstd * gv.w + bv.w);
  *(bf16x4*)(out + (size_t)row * 1024 + tid * 4) = o;
}

// ---------------- LayerNorm bf16-in variant (residual stream), dim=1024 ------
__global__ __launch_bounds__(256) void layernorm_b16(
    const bf16_t* __restrict__ x, const float* __restrict__ g, const float* __restrict__ b,
    bf16_t* __restrict__ out)
{
  const int row = blockIdx.x, tid = threadIdx.x;
  const bf16x4 xv = *(const bf16x4*)(x + (size_t)row * 1024 + tid * 4);
  float v0 = (float)xv[0], v1 = (float)xv[1], v2 = (float)xv[2], v3 = (float)xv[3];
  float s = v0 + v1 + v2 + v3;
  float s2 = v0 * v0 + v1 * v1 + v2 * v2 + v3 * v3;
#pragma unroll
  for (int off = 32; off > 0; off >>= 1) {
    s += __shfl_down(s, off);
    s2 += __shfl_down(s2, off);
  }
  __shared__ float ps[4], ps2[4];
  const int lane = tid & 63, wave = tid >> 6;
  if (lane == 0) { ps[wave] = s; ps2[wave] = s2; }
  __syncthreads();
  s = ps[0] + ps[1] + ps[2] + ps[3];
  s2 = ps2[0] + ps2[1] + ps2[2] + ps2[3];
  const float mu = s * (1.f / 1024.f);
  const float var = s2 * (1.f / 1024.f) - mu * mu;
  const float rstd = rsqrtf(var + 1e-5f);
  const float4 gv = ((const float4*)g)[tid];
  const float4 bv = ((const float4*)b)[tid];
  bf16x4 o;
  o[0] = (bf16_t)((v0 - mu) * rstd * gv.x + bv.x);
  o[1] = (bf16_t)((v1 - mu) * rstd * gv.y + bv.y);
  o[2] = (bf16_t)((v2 - mu) * rstd * gv.z + bv.z);
  o[3] = (bf16_t)((v3 - mu) * rstd * gv.w + bv.w);
  *(bf16x4*)(out + (size_t)row * 1024 + tid * 4) = o;
}

// ---------------- weight transpose fp32[K,N] -> bf16[N,K], per-layer in grid.z ----------------
__global__ void transpose_to_bf16(const float* __restrict__ src, bf16_t* __restrict__ dst, int K, int N)
{
  __shared__ float tile[32][33];
  const size_t loff = (size_t)blockIdx.z * K * N;
  src += loff; dst += loff;
  const int k0 = blockIdx.y * 32, n0 = blockIdx.x * 32;
  const int tx = threadIdx.x, ty = threadIdx.y;
#pragma unroll
  for (int i = ty; i < 32; i += 8)
    tile[i][tx] = src[(size_t)(k0 + i) * N + n0 + tx];
  __syncthreads();
#pragma unroll
  for (int i = ty; i < 32; i += 8)
    dst[(size_t)(n0 + i) * K + k0 + tx] = (bf16_t)tile[tx][i];
}

__global__ void f32_to_bf16(const float* __restrict__ src, bf16_t* __restrict__ dst, int n4)
{
  int i = blockIdx.x * blockDim.x + threadIdx.x;
  if (i < n4) {
    float4 v = ((const float4*)src)[i];
    bf16x4 o;
    o[0] = (bf16_t)v.x; o[1] = (bf16_t)v.y; o[2] = (bf16_t)v.z; o[3] = (bf16_t)v.w;
    ((bf16x4*)dst)[i] = o;
  }
}

extern "C" void kernel_launch(void* const* d_in, const int* in_sizes, int n_in,
                              void* d_out, int out_size, void* d_ws, size_t ws_size,
                              hipStream_t stream)
{
  const float* x      = (const float*)d_in[0];
  const float* ctx    = (const float*)d_in[1];
  const float* ln1_g  = (const float*)d_in[2];
  const float* ln1_b  = (const float*)d_in[3];
  const float* w_qkv  = (const float*)d_in[4];
  const float* w_sa_o = (const float*)d_in[5];
  const float* b_sa_o = (const float*)d_in[6];
  const float* ln2_g  = (const float*)d_in[7];
  const float* ln2_b  = (const float*)d_in[8];
  const float* w_q    = (const float*)d_in[9];
  const float* w_kv   = (const float*)d_in[10];
  const float* w_ca_o = (const float*)d_in[11];
  const float* b_ca_o = (const float*)d_in[12];
  const float* ln3_g  = (const float*)d_in[13];
  const float* ln3_b  = (const float*)d_in[14];
  const float* w_ff1  = (const float*)d_in[15];
  const float* b_ff1  = (const float*)d_in[16];
  const float* w_ff2  = (const float*)d_in[17];
  const float* b_ff2  = (const float*)d_in[18];

  char* p = (char*)d_ws;
  auto alloc = [&](size_t bytes) { char* r = p; p += (bytes + 255) & ~(size_t)255; return r; };
  bf16_t* wqkv_t = (bf16_t*)alloc((size_t)NDEPTH * 3072 * 1024 * 2);
  bf16_t* wsao_t = (bf16_t*)alloc((size_t)NDEPTH * 1024 * 1024 * 2);
  bf16_t* wq_t   = (bf16_t*)alloc((size_t)NDEPTH * 1024 * 1024 * 2);
  bf16_t* wkv_t  = (bf16_t*)alloc((size_t)NDEPTH * 2048 * 768 * 2);
  bf16_t* wcao_t = (bf16_t*)alloc((size_t)NDEPTH * 1024 * 1024 * 2);
  bf16_t* wff1_t = (bf16_t*)alloc((size_t)NDEPTH * 4096 * 1024 * 2);
  bf16_t* wff2_t = (bf16_t*)alloc((size_t)NDEPTH * 1024 * 4096 * 2);
  bf16_t* ctxb   = (bf16_t*)alloc((size_t)NCTX * CTXD * 2);
  bf16_t* xbuf   = (bf16_t*)alloc((size_t)NTOK * DIM * 2);    // bf16 residual stream
  bf16_t* lnbuf  = (bf16_t*)alloc((size_t)NTOK * DIM * 2);    // also attention out
  bf16_t* bigbuf = (bf16_t*)alloc((size_t)NTOK * 4096 * 2);   // qkv / ff1 out
  bf16_t* qbuf   = (bf16_t*)alloc((size_t)NTOK * DIM * 2);
  bf16_t* kvbuf  = (bf16_t*)alloc((size_t)NCTX * 2048 * 2);
  bf16_t* vtbuf  = (bf16_t*)alloc((size_t)32 * 64 * 2048 * 2);  // self V^T [b*h][d][key]
  bf16_t* vtcbuf = (bf16_t*)alloc((size_t)32 * 64 * 1024 * 2);  // cross V^T
  if ((size_t)(p - (char*)d_ws) > ws_size) return;  // workspace too small: fail loudly

  dim3 tb(32, 8);
  transpose_to_bf16<<<dim3(3072 / 32, 1024 / 32, NDEPTH), tb, 0, stream>>>(w_qkv, wqkv_t, 1024, 3072);
  transpose_to_bf16<<<dim3(1024 / 32, 1024 / 32, NDEPTH), tb, 0, stream>>>(w_sa_o, wsao_t, 1024, 1024);
  transpose_to_bf16<<<dim3(1024 / 32, 1024 / 32, NDEPTH), tb, 0, stream>>>(w_q, wq_t, 1024, 1024);
  transpose_to_bf16<<<dim3(2048 / 32, 768 / 32, NDEPTH), tb, 0, stream>>>(w_kv, wkv_t, 768, 2048);
  transpose_to_bf16<<<dim3(1024 / 32, 1024 / 32, NDEPTH), tb, 0, stream>>>(w_ca_o, wcao_t, 1024, 1024);
  transpose_to_bf16<<<dim3(4096 / 32, 1024 / 32, NDEPTH), tb, 0, stream>>>(w_ff1, wff1_t, 1024, 4096);
  transpose_to_bf16<<<dim3(1024 / 32, 4096 / 32, NDEPTH), tb, 0, stream>>>(w_ff2, wff2_t, 4096, 1024);
  f32_to_bf16<<<(NCTX * CTXD / 4 + 255) / 256, 256, 0, stream>>>(ctx, ctxb, NCTX * CTXD / 4);

  for (int i = 0; i < NDEPTH; ++i) {
    // ---- self-attention ----
    if (i == 0)
      layernorm_f32<<<NTOK, 256, 0, stream>>>(x, ln1_g, ln1_b, lnbuf);
    else
      layernorm_b16<<<NTOK, 256, 0, stream>>>(xbuf, ln1_g + i * DIM, ln1_b + i * DIM, lnbuf);
    gemm_bf16<0><<<dim3(3072 / 128, NTOK / 128), 512, 0, stream>>>(
        lnbuf, wqkv_t + (size_t)i * 3072 * 1024, nullptr, nullptr, bigbuf, NTOK, 3072, 1024);
    v_transpose<<<dim3(2048 / 32, 2, 32), tb, 0, stream>>>(bigbuf + 2048, 3072, vtbuf, 2048);
    attn_fwd<<<dim3(2048 / 64, NHEADS, 2), 256, 0, stream>>>(
        bigbuf, 3072, bigbuf + 1024, 3072, vtbuf, lnbuf, 1024, 2048, 2048);
    if (i == 0)
      gemm64_bf16<4><<<dim3(1024 / 64, NTOK / 64), 256, 0, stream>>>(
          lnbuf, wsao_t, b_sa_o, x, xbuf, NTOK, 1024, 1024);
    else
      gemm64_bf16<3><<<dim3(1024 / 64, NTOK / 64), 256, 0, stream>>>(
          lnbuf, wsao_t + (size_t)i * 1024 * 1024, b_sa_o + i * DIM, xbuf, xbuf, NTOK, 1024, 1024);
    // ---- cross-attention ----
    layernorm_b16<<<NTOK, 256, 0, stream>>>(xbuf, ln2_g + i * DIM, ln2_b + i * DIM, lnbuf);
    gemm64_bf16<0><<<dim3(1024 / 64, NTOK / 64), 256, 0, stream>>>(
        lnbuf, wq_t + (size_t)i * 1024 * 1024, nullptr, nullptr, qbuf, NTOK, 1024, 1024);
    gemm64_bf16<0><<<dim3(2048 / 64, NCTX / 64), 256, 0, stream>>>(
        ctxb, wkv_t + (size_t)i * 2048 * 768, nullptr, nullptr, kvbuf, NCTX, 2048, 768);
    v_transpose<<<dim3(1024 / 32, 2, 32), tb, 0, stream>>>(kvbuf + 1024, 2048, vtcbuf, 1024);
    attn_fwd<<<dim3(2048 / 64, NHEADS, 2), 256, 0, stream>>>(
        qbuf, 1024, kvbuf, 2048, vtcbuf, lnbuf, 1024, 2048, 1024);
    gemm64_bf16<3><<<dim3(1024 / 64, NTOK / 64), 256, 0, stream>>>(
        lnbuf, wcao_t + (size_t)i * 1024 * 1024, b_ca_o + i * DIM, xbuf, xbuf, NTOK, 1024, 1024);
    // ---- feed-forward ----
    layernorm_b16<<<NTOK, 256, 0, stream>>>(xbuf, ln3_g + i * DIM, ln3_b + i * DIM, lnbuf);
    gemm_bf16<2><<<dim3(4096 / 128, NTOK / 128), 512, 0, stream>>>(
        lnbuf, wff1_t + (size_t)i * 4096 * 1024, b_ff1 + i * MLP_DIM, nullptr, bigbuf, NTOK, 4096, 1024);
    if (i == NDEPTH - 1)
      gemm64_bf16<5><<<dim3(1024 / 64, NTOK / 64), 256, 0, stream>>>(
          bigbuf, wff2_t + (size_t)i * 1024 * 4096, b_ff2 + i * DIM, xbuf, d_out, NTOK, 1024, 4096);
    else
      gemm64_bf16<3><<<dim3(1024 / 64, NTOK / 64), 256, 0, stream>>>(
          bigbuf, wff2_t + (size_t)i * 1024 * 4096, b_ff2 + i * DIM, xbuf, xbuf, NTOK, 1024, 4096);
  }
}